// Round 9
// baseline (35.936 us; speedup 1.0000x reference)
//
#include <hip/hip_runtime.h>
#include <math.h>

#define NB 16
#define NQ 900
#define NQP 912             // padded teacher count (4 phases x 228)
#define PPH 228             // teachers per phase (per wave)
#define NC 80
#define EPSV 1e-7f
#define IOU_THR 0.1f
#define SPB 64              // students per block (one per lane)
#define CHB 15              // blocks per batch (15*64 = 960 >= 900)
#define NBLK (NB * CHB)     // 240

__device__ __forceinline__ float sigm(float x) { return 1.0f / (1.0f + __expf(-x)); }

// ---- K1: lane-per-student argmax (wave-uniform teacher broadcast) + BCE/conf ----
__global__ __launch_bounds__(256) void k_main(
    const float* __restrict__ s_logits,
    const float* __restrict__ s_boxes,
    const float* __restrict__ t_logits,
    const float* __restrict__ t_boxes,
    int*    __restrict__ g_cnt,     // [NB*NQ] zeroed by memset node; cnt[b,j] += 1
    float*  __restrict__ g_v,       // [NB*NQ] flag-gated 5*l1+2*(1-giou), else 0
    float2* __restrict__ g_part)    // [NBLK]  (bce_sum, conf_any)
{
    __shared__ float4 tcor[NQP];    // x1, x2, y1, y2 (pad: impossible boxes -> iou 0)
    __shared__ float  tarea[NQP];
    __shared__ float  candv[4][SPB];
    __shared__ int    candi[4][SPB];
    __shared__ int    lidx[SPB];
    __shared__ float  sconf0;
    __shared__ float2 sres[SPB];    // per-row (bce_mean, conf)

    const int bx  = blockIdx.x;     // 0..14
    const int b   = blockIdx.y;     // 0..15
    const int tid = threadIdx.x;
    const int wv  = tid >> 6, lane = tid & 63;

    if (tid < SPB) sres[tid] = make_float2(0.f, 0.f);

    // stage teacher boxes of batch b (padded to 912)
    const float4* tb = (const float4*)(t_boxes + b * NQ * 4);
    for (int i = tid; i < NQP; i += 256) {
        if (i < NQ) {
            float4 t = tb[i];
            float hw = t.z * 0.5f, hh = t.w * 0.5f;
            tcor[i]  = make_float4(t.x - hw, t.x + hw, t.y - hh, t.y + hh);
            tarea[i] = t.z * t.w;
        } else {
            tcor[i]  = make_float4(2e9f, -2e9f, 2e9f, -2e9f);  // inter == 0 exactly
            tarea[i] = 1.0f;
        }
    }
    // conf0[b] (one wave; redundant per block but cheap)
    if (tid < 64) {
        const float* tl = t_logits + b * NQ * NC;   // teacher row 0 of batch b
        float m = tl[tid];
        if (tid < NC - 64) m = fmaxf(m, tl[tid + 64]);
        for (int s = 32; s >= 1; s >>= 1) m = fmaxf(m, __shfl_xor(m, s, 64));
        if (tid == 0) sconf0 = (sigm(m) > 0.2f) ? 1.0f : 0.0f;
    }
    __syncthreads();

    // ---- argmax IoU: lane = student, wave = contiguous 228-teacher phase ----
    const int sq  = bx * SPB + lane;
    const bool act = (sq < NQ);
    float4 sb = make_float4(0.f, 0.f, 0.f, 0.f);
    if (act) sb = ((const float4*)(s_boxes + b * NQ * 4))[sq];
    const float shw = sb.z * 0.5f, shh = sb.w * 0.5f;
    const float sx1 = sb.x - shw, sx2 = sb.x + shw;
    const float sy1 = sb.y - shh, sy2 = sb.y + shh;
    const float sarea = sb.z * sb.w;

    // 4 interleaved slot accumulators (ILP); slot k covers t = base + 4*i + k
    float bv0 = -1.f, bv1 = -1.f, bv2 = -1.f, bv3 = -1.f;
    int   bi0 = 0,    bi1 = 0,    bi2 = 0,    bi3 = 0;
    const int tb0 = wv * PPH;
#define IOU_STEP(T, BV, BI)                                                    \
    {                                                                          \
        float4 c = tcor[(T)];                                                  \
        float iw = fminf(sx2, c.y) - fmaxf(sx1, c.x);                          \
        float ih = fminf(sy2, c.w) - fmaxf(sy1, c.z);                          \
        float inter = fmaxf(iw, 0.0f) * fmaxf(ih, 0.0f);                       \
        float uni = sarea + tarea[(T)] - inter + EPSV;                         \
        float iou = inter * __frcp_rn(uni);                                    \
        if (iou > BV) { BV = iou; BI = (T); }                                  \
    }
    for (int i = 0; i < PPH; i += 4) {
        int t = tb0 + i;
        IOU_STEP(t + 0, bv0, bi0)
        IOU_STEP(t + 1, bv1, bi1)
        IOU_STEP(t + 2, bv2, bi2)
        IOU_STEP(t + 3, bv3, bi3)
    }
#undef IOU_STEP
    // combine slots (ties -> lower teacher index = argmax first-occurrence)
    float best = bv0; int bidx = bi0;
    if (bv1 > best || (bv1 == best && bi1 < bidx)) { best = bv1; bidx = bi1; }
    if (bv2 > best || (bv2 == best && bi2 < bidx)) { best = bv2; bidx = bi2; }
    if (bv3 > best || (bv3 == best && bi3 < bidx)) { best = bv3; bidx = bi3; }
    candv[wv][lane] = best; candi[wv][lane] = bidx;
    __syncthreads();

    // ---- cross-wave combine (wave 0) + per-student outputs ----
    if (wv == 0) {
        float bst = candv[0][lane]; int bix = candi[0][lane];
        #pragma unroll
        for (int p = 1; p < 4; ++p) {
            float ov = candv[p][lane]; int oi = candi[p][lane];
            if (ov > bst || (ov == bst && oi < bix)) { bst = ov; bix = oi; }
        }
        if (act) {
            int o = b * NQ + sq;
            lidx[lane] = bix;
            atomicAdd(&g_cnt[b * NQ + bix], 1);   // relaxed scatter (deterministic)
            // L1 and (1 - GIoU) vs teacher box 0 (exact divides like ref)
            float4 t0 = tb[0];
            float4 c  = tcor[0];
            float iw = fminf(sx2, c.y) - fmaxf(sx1, c.x);
            float ih = fminf(sy2, c.w) - fmaxf(sy1, c.z);
            float inter = fmaxf(iw, 0.0f) * fmaxf(ih, 0.0f);
            float uni = sarea + tarea[0] - inter + EPSV;
            float iou = inter / uni;
            float cw = fmaxf(sx2, c.y) - fminf(sx1, c.x);
            float ch = fmaxf(sy2, c.w) - fminf(sy1, c.z);
            float carea = cw * ch + EPSV;
            float giou1 = 1.0f - (iou - (carea - uni) / carea);
            float l1 = fabsf(sb.x - t0.x) + fabsf(sb.y - t0.y) +
                       fabsf(sb.z - t0.z) + fabsf(sb.w - t0.w);
            float v = 0.0f;
            if (sconf0 > 0.0f && bst > IOU_THR) v = 5.0f * l1 + 2.0f * giou1;
            g_v[o] = v;
        }
    }
    __syncthreads();

    // ---- BCE + conf: 16-lane group per row; 16 rows/pass, 4 passes ----
    const int grp = lane >> 4, tc2 = lane & 15;
    #pragma unroll
    for (int p = 0; p < 4; ++p) {
        const int r   = p * 16 + wv * 4 + grp;     // 0..63, unique per pass
        const int sq2 = bx * SPB + r;
        if (sq2 < NQ) {
            int row = b * NQ + sq2;
            int j   = lidx[r];                 // flat idx -> batch-0 teacher row (ref quirk)
            const float* srow = s_logits + row * NC;
            const float* trow = t_logits + row * NC;
            const float* grow = t_logits + j * NC;
            float4 svv = *(const float4*)(srow + tc2 * 4);
            float4 tvv = *(const float4*)(trow + tc2 * 4);
            float4 gvv = *(const float4*)(grow + tc2 * 4);
            float  s4 = srow[64 + tc2];
            float  t4 = trow[64 + tc2];
            float  g4 = grow[64 + tc2];
            float bce = 0.f;
            {
                float se[5] = {svv.x, svv.y, svv.z, svv.w, s4};
                float ge[5] = {gvv.x, gvv.y, gvv.z, gvv.w, g4};
                #pragma unroll
                for (int e = 0; e < 5; ++e) {
                    float s0 = se[e], g0 = ge[e];
                    bce += fmaxf(s0, 0.f) + __logf(1.0f + __expf(-fabsf(s0)))
                         - s0 * __builtin_amdgcn_rcpf(1.0f + __expf(-g0));
                }
            }
            float tmax = fmaxf(fmaxf(fmaxf(tvv.x, tvv.y), fmaxf(tvv.z, tvv.w)), t4);
            for (int m = 8; m >= 1; m >>= 1) {
                bce  += __shfl_xor(bce, m, 64);
                tmax  = fmaxf(tmax, __shfl_xor(tmax, m, 64));
            }
            if (tc2 == 0)
                sres[r] = make_float2(bce * (1.0f / (float)NC),
                                      (sigm(tmax) > 0.2f) ? 1.0f : 0.0f);
        }
    }
    __syncthreads();
    if (tid < 64) {
        float2 pr = sres[tid];
        float bs = pr.x, ca = pr.y;
        for (int m = 32; m >= 1; m >>= 1) {
            bs += __shfl_xor(bs, m, 64);
            ca  = fmaxf(ca, __shfl_xor(ca, m, 64));
        }
        if (tid == 0) g_part[b * CHB + bx] = make_float2(bs, ca);
    }
}

// ---- K2: single block — coalesced cnt·v dot + partial reduce + finalize ----
__global__ __launch_bounds__(1024) void k_final(
    const int*    __restrict__ g_cnt,
    const float*  __restrict__ g_v,
    const float2* __restrict__ g_part,
    const int*    __restrict__ tn_p,
    float* __restrict__ out)
{
    const int tid = threadIdx.x;
    float bs = 0.f, ca = 0.f;
    if (tid < NBLK) { float2 p = g_part[tid]; bs = p.x; ca = p.y; }
    float vs = 0.f;
    #pragma unroll
    for (int k = 0; k < 15; ++k) {
        int i = tid + k * 1024;
        if (i < NB * NQ) vs += (float)g_cnt[i] * g_v[i];   // coalesced, no indirection
    }
    __shared__ float rb[16], rv[16], rc[16];
    const int wv = tid >> 6, lane = tid & 63;
    for (int m = 32; m >= 1; m >>= 1) {
        bs += __shfl_xor(bs, m, 64);
        vs += __shfl_xor(vs, m, 64);
        ca  = fmaxf(ca, __shfl_xor(ca, m, 64));
    }
    if (lane == 0) { rb[wv] = bs; rv[wv] = vs; rc[wv] = ca; }
    __syncthreads();
    if (tid == 0) {
        float sb = 0.f, sv = 0.f, sc = 0.f;
        for (int k = 0; k < 16; ++k) { sb += rb[k]; sv += rv[k]; sc = fmaxf(sc, rc[k]); }
        float tn = (float)tn_p[0];
        out[0] = (sc > 0.f) ? (sv + sb) / tn : 0.0f;
    }
}

extern "C" void kernel_launch(void* const* d_in, const int* in_sizes, int n_in,
                              void* d_out, int out_size, void* d_ws, size_t ws_size,
                              hipStream_t stream) {
    const float* s_logits = (const float*)d_in[0];
    const float* s_boxes  = (const float*)d_in[1];
    const float* t_logits = (const float*)d_in[2];
    const float* t_boxes  = (const float*)d_in[3];
    const int*   tn       = (const int*)d_in[4];
    float* out = (float*)d_out;

    char* ws = (char*)d_ws;
    int*    g_cnt  = (int*)(ws);              // 14400 i32 @ 0 (zeroed per call)
    float*  g_v    = (float*)(ws + 57600);    // 14400 f32
    float2* g_part = (float2*)(ws + 115200);  // 240 float2

    hipMemsetAsync(g_cnt, 0, NB * NQ * sizeof(int), stream);
    k_main<<<dim3(CHB, NB), 256, 0, stream>>>(s_logits, s_boxes, t_logits, t_boxes,
                                              g_cnt, g_v, g_part);
    k_final<<<1, 1024, 0, stream>>>(g_cnt, g_v, g_part, tn, out);
}

// Round 10
// 30.037 us; speedup vs baseline: 1.1964x; 1.1964x over previous
//
#include <hip/hip_runtime.h>
#include <math.h>

#define NB 16
#define NQ 900
#define NQP 928             // padded teacher count (58*16)
#define NC 80
#define EPSV 1e-7f
#define IOU_THR 0.1f
#define SPB 16              // students per block
#define CHB 57              // blocks per batch (57*16 = 912 >= 900)
#define NBLK (NB * CHB)     // 912

__device__ __forceinline__ float sigm(float x) { return 1.0f / (1.0f + __expf(-x)); }

// ---- K1: per-(b, 16 students): IoU argmax (16-lane split, 2-slot ILP) + BCE/conf ----
__global__ __launch_bounds__(256) void k_main(
    const float* __restrict__ s_logits,
    const float* __restrict__ s_boxes,
    const float* __restrict__ t_logits,
    const float* __restrict__ t_boxes,
    int*    __restrict__ g_cnt,     // [NB*NQ] zeroed by memset node; cnt[b,j] += 1
    float*  __restrict__ g_v,       // [NB*NQ] flag-gated 5*l1+2*(1-giou), else 0
    float2* __restrict__ g_part)    // [NBLK]  (bce_sum, conf_any)
{
    __shared__ float4 tcor[NQP];    // x1, x2, y1, y2 (pad: impossible boxes -> iou 0)
    __shared__ float  tarea[NQP];
    __shared__ int    lidx[SPB];
    __shared__ float  sconf0;
    __shared__ float2 sres[SPB];    // per-row (bce_mean, conf)

    const int bx  = blockIdx.x;     // 0..56
    const int b   = blockIdx.y;     // 0..15
    const int tid = threadIdx.x;

    // stage teacher boxes of batch b (padded to 928)
    const float4* tb = (const float4*)(t_boxes + b * NQ * 4);
    for (int i = tid; i < NQP; i += 256) {
        if (i < NQ) {
            float4 t = tb[i];
            float hw = t.z * 0.5f, hh = t.w * 0.5f;
            tcor[i]  = make_float4(t.x - hw, t.x + hw, t.y - hh, t.y + hh);
            tarea[i] = t.z * t.w;
        } else {
            tcor[i]  = make_float4(2e9f, -2e9f, 2e9f, -2e9f);  // inter == 0 exactly
            tarea[i] = 1.0f;
        }
    }
    // conf0[b] (one wave; redundant per block but cheap)
    if (tid < 64) {
        const float* tl = t_logits + b * NQ * NC;   // teacher row 0 of batch b
        float m = tl[tid];
        if (tid < NC - 64) m = fmaxf(m, tl[tid + 64]);
        for (int s = 32; s >= 1; s >>= 1) m = fmaxf(m, __shfl_xor(m, s, 64));
        if (tid == 0) sconf0 = (sigm(m) > 0.2f) ? 1.0f : 0.0f;
    }
    __syncthreads();

    // ---- argmax IoU over 900(+pad) teachers; 16 lanes per student, 2 ILP slots ----
    const int s  = tid >> 4;        // 0..15
    const int tc = tid & 15;        // teacher phase
    const int sq = bx * SPB + s;
    const bool act = (sq < NQ);
    float4 sb = make_float4(0.f, 0.f, 0.f, 0.f);
    if (act) sb = ((const float4*)(s_boxes + b * NQ * 4))[sq];
    const float shw = sb.z * 0.5f, shh = sb.w * 0.5f;
    const float sx1 = sb.x - shw, sx2 = sb.x + shw;
    const float sy1 = sb.y - shh, sy2 = sb.y + shh;
    const float sarea = sb.z * sb.w;

    float bvA = -1.0f, bvB = -1.0f; int biA = 0, biB = 0;
    #pragma unroll 4
    for (int i = 0; i < 29; ++i) {
        {   // slot A: t in [tc, 464) step 16
            int t = tc + (i << 4);
            float4 c = tcor[t];
            float iw = fminf(sx2, c.y) - fmaxf(sx1, c.x);
            float ih = fminf(sy2, c.w) - fmaxf(sy1, c.z);
            float inter = fmaxf(iw, 0.0f) * fmaxf(ih, 0.0f);
            float uni = sarea + tarea[t] - inter + EPSV;
            float iou = inter * __frcp_rn(uni);
            if (iou > bvA) { bvA = iou; biA = t; }   // strictly greater
        }
        {   // slot B: t in [464+tc, 928) step 16 (indices all > slot A's)
            int t = tc + ((i + 29) << 4);
            float4 c = tcor[t];
            float iw = fminf(sx2, c.y) - fmaxf(sx1, c.x);
            float ih = fminf(sy2, c.w) - fmaxf(sy1, c.z);
            float inter = fmaxf(iw, 0.0f) * fmaxf(ih, 0.0f);
            float uni = sarea + tarea[t] - inter + EPSV;
            float iou = inter * __frcp_rn(uni);
            if (iou > bvB) { bvB = iou; biB = t; }   // strictly greater
        }
    }
    // merge slots: B's indices are strictly greater -> replace only on strict >
    float best = bvA; int bidx = biA;
    if (bvB > best) { best = bvB; bidx = biB; }
    // combine 16 phases; ties -> lower index (argmax first-occurrence)
    for (int m = 1; m <= 8; m <<= 1) {
        float ov = __shfl_xor(best, m, 64);
        int   oi = __shfl_xor(bidx, m, 64);
        if (ov > best || (ov == best && oi < bidx)) { best = ov; bidx = oi; }
    }
    if (act && tc == 0) {
        int o = b * NQ + sq;
        lidx[s] = bidx;
        atomicAdd(&g_cnt[b * NQ + bidx], 1);    // relaxed int scatter (deterministic)
        // L1 and (1 - GIoU) vs teacher box 0 (exact divides like ref)
        float4 t0 = tb[0];
        float4 c  = tcor[0];
        float iw = fminf(sx2, c.y) - fmaxf(sx1, c.x);
        float ih = fminf(sy2, c.w) - fmaxf(sy1, c.z);
        float inter = fmaxf(iw, 0.0f) * fmaxf(ih, 0.0f);
        float uni = sarea + tarea[0] - inter + EPSV;
        float iou = inter / uni;
        float cw = fmaxf(sx2, c.y) - fminf(sx1, c.x);
        float ch = fmaxf(sy2, c.w) - fminf(sy1, c.z);
        float carea = cw * ch + EPSV;
        float giou1 = 1.0f - (iou - (carea - uni) / carea);
        float l1 = fabsf(sb.x - t0.x) + fabsf(sb.y - t0.y) +
                   fabsf(sb.z - t0.z) + fabsf(sb.w - t0.w);
        float v = 0.0f;
        if (sconf0 > 0.0f && best > IOU_THR) v = 5.0f * l1 + 2.0f * giou1;
        g_v[o] = v;
    }
    __syncthreads();

    // ---- BCE + conf: 16-lane group per row; float4 + scalar loads ----
    const int wv  = tid >> 6, lane = tid & 63;
    const int grp = lane >> 4, tc2 = lane & 15;
    const int s2  = wv * 4 + grp;              // 0..15
    const int sq2 = bx * SPB + s2;
    if (sq2 < NQ) {
        int row = b * NQ + sq2;
        int j   = lidx[s2];                    // flat idx -> batch-0 teacher row (ref quirk)
        const float* srow = s_logits + row * NC;
        const float* trow = t_logits + row * NC;
        const float* grow = t_logits + j * NC;
        float4 svv = *(const float4*)(srow + tc2 * 4);
        float4 tvv = *(const float4*)(trow + tc2 * 4);
        float4 gvv = *(const float4*)(grow + tc2 * 4);
        float  s4 = srow[64 + tc2];
        float  t4 = trow[64 + tc2];
        float  g4 = grow[64 + tc2];
        float bce = 0.f;
        {
            float se[5] = {svv.x, svv.y, svv.z, svv.w, s4};
            float ge[5] = {gvv.x, gvv.y, gvv.z, gvv.w, g4};
            #pragma unroll
            for (int e = 0; e < 5; ++e) {
                float s0 = se[e], g0 = ge[e];
                bce += fmaxf(s0, 0.f) + __logf(1.0f + __expf(-fabsf(s0)))
                     - s0 * __builtin_amdgcn_rcpf(1.0f + __expf(-g0));
            }
        }
        float tmax = fmaxf(fmaxf(fmaxf(tvv.x, tvv.y), fmaxf(tvv.z, tvv.w)), t4);
        for (int m = 8; m >= 1; m >>= 1) {
            bce  += __shfl_xor(bce, m, 64);
            tmax  = fmaxf(tmax, __shfl_xor(tmax, m, 64));
        }
        if (tc2 == 0)
            sres[s2] = make_float2(bce * (1.0f / (float)NC),
                                   (sigm(tmax) > 0.2f) ? 1.0f : 0.0f);
    }
    __syncthreads();
    if (tid < 64) {
        float bs = 0.f, ca = 0.f;
        if (tid < SPB) { float2 p = sres[tid]; bs = p.x; ca = p.y; }
        for (int m = 32; m >= 1; m >>= 1) {
            bs += __shfl_xor(bs, m, 64);
            ca  = fmaxf(ca, __shfl_xor(ca, m, 64));
        }
        if (tid == 0) g_part[b * CHB + bx] = make_float2(bs, ca);
    }
}

// ---- K2: single block — coalesced cnt·v dot + partial reduce + finalize ----
__global__ __launch_bounds__(1024) void k_final(
    const int*    __restrict__ g_cnt,
    const float*  __restrict__ g_v,
    const float2* __restrict__ g_part,
    const int*    __restrict__ tn_p,
    float* __restrict__ out)
{
    const int tid = threadIdx.x;
    float bs = 0.f, ca = 0.f;
    if (tid < NBLK) { float2 p = g_part[tid]; bs = p.x; ca = p.y; }
    float vs = 0.f;
    #pragma unroll
    for (int k = 0; k < 15; ++k) {
        int i = tid + k * 1024;
        if (i < NB * NQ) vs += (float)g_cnt[i] * g_v[i];   // coalesced, no indirection
    }
    __shared__ float rb[16], rv[16], rc[16];
    const int wv = tid >> 6, lane = tid & 63;
    for (int m = 32; m >= 1; m >>= 1) {
        bs += __shfl_xor(bs, m, 64);
        vs += __shfl_xor(vs, m, 64);
        ca  = fmaxf(ca, __shfl_xor(ca, m, 64));
    }
    if (lane == 0) { rb[wv] = bs; rv[wv] = vs; rc[wv] = ca; }
    __syncthreads();
    if (tid == 0) {
        float sb = 0.f, sv = 0.f, sc = 0.f;
        for (int k = 0; k < 16; ++k) { sb += rb[k]; sv += rv[k]; sc = fmaxf(sc, rc[k]); }
        float tn = (float)tn_p[0];
        out[0] = (sc > 0.f) ? (sv + sb) / tn : 0.0f;
    }
}

extern "C" void kernel_launch(void* const* d_in, const int* in_sizes, int n_in,
                              void* d_out, int out_size, void* d_ws, size_t ws_size,
                              hipStream_t stream) {
    const float* s_logits = (const float*)d_in[0];
    const float* s_boxes  = (const float*)d_in[1];
    const float* t_logits = (const float*)d_in[2];
    const float* t_boxes  = (const float*)d_in[3];
    const int*   tn       = (const int*)d_in[4];
    float* out = (float*)d_out;

    char* ws = (char*)d_ws;
    int*    g_cnt  = (int*)(ws);              // 14400 i32 @ 0 (zeroed per call)
    float*  g_v    = (float*)(ws + 57600);    // 14400 f32
    float2* g_part = (float2*)(ws + 115200);  // 912 float2

    hipMemsetAsync(g_cnt, 0, NB * NQ * sizeof(int), stream);
    k_main<<<dim3(CHB, NB), 256, 0, stream>>>(s_logits, s_boxes, t_logits, t_boxes,
                                              g_cnt, g_v, g_part);
    k_final<<<1, 1024, 0, stream>>>(g_cnt, g_v, g_part, tn, out);
}

// Round 12
// 29.403 us; speedup vs baseline: 1.2222x; 1.0215x over previous
//
#include <hip/hip_runtime.h>
#include <math.h>

#define NB 16
#define NQ 900
#define NQP 928             // padded teacher count (58*16)
#define NC 80
#define EPSV 1e-7f
#define IOU_THR 0.1f
#define SPB 16              // students per block
#define CHB 57              // blocks per batch (57*16 = 912 >= 900)
#define NBLK (NB * CHB)     // 912

__device__ __forceinline__ float sigm(float x) { return 1.0f / (1.0f + __expf(-x)); }

// ---- K1: per-(b, 16 students): IoU argmax (16-lane split, 2 ILP slots) + BCE/conf ----
__global__ __launch_bounds__(256) void k_main(
    const float* __restrict__ s_logits,
    const float* __restrict__ s_boxes,
    const float* __restrict__ t_logits,
    const float* __restrict__ t_boxes,
    int*    __restrict__ g_idx,     // [NB*NQ] argmax teacher index (plain store)
    float*  __restrict__ g_v,       // [NB*NQ] flag-gated 5*l1+2*(1-giou), else 0
    float2* __restrict__ g_part)    // [NBLK]  (bce_sum, conf_any)
{
    __shared__ float4 tcor[NQP];    // x1, x2, y1, y2 (pad: impossible boxes -> iou 0)
    __shared__ float  tarea[NQP];
    __shared__ int    lidx[SPB];
    __shared__ float  sconf0;
    __shared__ float2 sres[SPB];    // per-row (bce_mean, conf)

    const int bx  = blockIdx.x;     // 0..56
    const int b   = blockIdx.y;     // 0..15
    const int tid = threadIdx.x;

    // stage teacher boxes of batch b (padded to 928)
    const float4* tb = (const float4*)(t_boxes + b * NQ * 4);
    for (int i = tid; i < NQP; i += 256) {
        if (i < NQ) {
            float4 t = tb[i];
            float hw = t.z * 0.5f, hh = t.w * 0.5f;
            tcor[i]  = make_float4(t.x - hw, t.x + hw, t.y - hh, t.y + hh);
            tarea[i] = t.z * t.w;
        } else {
            tcor[i]  = make_float4(2e9f, -2e9f, 2e9f, -2e9f);  // inter == 0 exactly
            tarea[i] = 1.0f;
        }
    }
    // conf0[b] (one wave; redundant per block but cheap)
    if (tid < 64) {
        const float* tl = t_logits + b * NQ * NC;   // teacher row 0 of batch b
        float m = tl[tid];
        if (tid < NC - 64) m = fmaxf(m, tl[tid + 64]);
        for (int s = 32; s >= 1; s >>= 1) m = fmaxf(m, __shfl_xor(m, s, 64));
        if (tid == 0) sconf0 = (sigm(m) > 0.2f) ? 1.0f : 0.0f;
    }
    __syncthreads();

    // ---- argmax IoU over 900(+pad) teachers; 16 lanes per student, 2 ILP slots ----
    const int s  = tid >> 4;        // 0..15
    const int tc = tid & 15;        // teacher phase
    const int sq = bx * SPB + s;
    const bool act = (sq < NQ);
    float4 sb = make_float4(0.f, 0.f, 0.f, 0.f);
    if (act) sb = ((const float4*)(s_boxes + b * NQ * 4))[sq];
    const float shw = sb.z * 0.5f, shh = sb.w * 0.5f;
    const float sx1 = sb.x - shw, sx2 = sb.x + shw;
    const float sy1 = sb.y - shh, sy2 = sb.y + shh;
    const float sarea = sb.z * sb.w;

    float bvA = -1.0f, bvB = -1.0f; int biA = 0, biB = 0;
    #pragma unroll 4
    for (int i = 0; i < 29; ++i) {
        {   // slot A: t in [tc, 464) step 16
            int t = tc + (i << 4);
            float4 c = tcor[t];
            float iw = fminf(sx2, c.y) - fmaxf(sx1, c.x);
            float ih = fminf(sy2, c.w) - fmaxf(sy1, c.z);
            float inter = fmaxf(iw, 0.0f) * fmaxf(ih, 0.0f);
            float uni = sarea + tarea[t] - inter + EPSV;
            float iou = inter * __frcp_rn(uni);
            if (iou > bvA) { bvA = iou; biA = t; }   // strictly greater
        }
        {   // slot B: t in [464+tc, 928) step 16 (indices all > slot A's)
            int t = tc + ((i + 29) << 4);
            float4 c = tcor[t];
            float iw = fminf(sx2, c.y) - fmaxf(sx1, c.x);
            float ih = fminf(sy2, c.w) - fmaxf(sy1, c.z);
            float inter = fmaxf(iw, 0.0f) * fmaxf(ih, 0.0f);
            float uni = sarea + tarea[t] - inter + EPSV;
            float iou = inter * __frcp_rn(uni);
            if (iou > bvB) { bvB = iou; biB = t; }   // strictly greater
        }
    }
    float best = bvA; int bidx = biA;
    if (bvB > best) { best = bvB; bidx = biB; }      // B's indices all greater
    // combine 16 phases; ties -> lower index (argmax first-occurrence)
    for (int m = 1; m <= 8; m <<= 1) {
        float ov = __shfl_xor(best, m, 64);
        int   oi = __shfl_xor(bidx, m, 64);
        if (ov > best || (ov == best && oi < bidx)) { best = ov; bidx = oi; }
    }
    if (act && tc == 0) {
        int o = b * NQ + sq;
        lidx[s]  = bidx;
        g_idx[o] = bidx;                        // plain store; kernel boundary = coherence
        // L1 and (1 - GIoU) vs teacher box 0 (exact divides like ref)
        float4 t0 = tb[0];
        float4 c  = tcor[0];
        float iw = fminf(sx2, c.y) - fmaxf(sx1, c.x);
        float ih = fminf(sy2, c.w) - fmaxf(sy1, c.z);
        float inter = fmaxf(iw, 0.0f) * fmaxf(ih, 0.0f);
        float uni = sarea + tarea[0] - inter + EPSV;
        float iou = inter / uni;
        float cw = fmaxf(sx2, c.y) - fminf(sx1, c.x);
        float ch = fmaxf(sy2, c.w) - fminf(sy1, c.z);
        float carea = cw * ch + EPSV;
        float giou1 = 1.0f - (iou - (carea - uni) / carea);
        float l1 = fabsf(sb.x - t0.x) + fabsf(sb.y - t0.y) +
                   fabsf(sb.z - t0.z) + fabsf(sb.w - t0.w);
        float v = 0.0f;
        if (sconf0 > 0.0f && best > IOU_THR) v = 5.0f * l1 + 2.0f * giou1;
        g_v[o] = v;
    }
    __syncthreads();

    // ---- BCE + conf: 16-lane group per row; float4 + scalar loads ----
    const int wv  = tid >> 6, lane = tid & 63;
    const int grp = lane >> 4, tc2 = lane & 15;
    const int s2  = wv * 4 + grp;              // 0..15
    const int sq2 = bx * SPB + s2;
    if (sq2 < NQ) {
        int row = b * NQ + sq2;
        int j   = lidx[s2];                    // flat idx -> batch-0 teacher row (ref quirk)
        const float* srow = s_logits + row * NC;
        const float* trow = t_logits + row * NC;
        const float* grow = t_logits + j * NC;
        float4 svv = *(const float4*)(srow + tc2 * 4);
        float4 tvv = *(const float4*)(trow + tc2 * 4);
        float4 gvv = *(const float4*)(grow + tc2 * 4);
        float  s4 = srow[64 + tc2];
        float  t4 = trow[64 + tc2];
        float  g4 = grow[64 + tc2];
        float bce = 0.f;
        {
            float se[5] = {svv.x, svv.y, svv.z, svv.w, s4};
            float ge[5] = {gvv.x, gvv.y, gvv.z, gvv.w, g4};
            #pragma unroll
            for (int e = 0; e < 5; ++e) {
                float s0 = se[e], g0 = ge[e];
                bce += fmaxf(s0, 0.f) + __logf(1.0f + __expf(-fabsf(s0)))
                     - s0 * __builtin_amdgcn_rcpf(1.0f + __expf(-g0));
            }
        }
        float tmax = fmaxf(fmaxf(fmaxf(tvv.x, tvv.y), fmaxf(tvv.z, tvv.w)), t4);
        for (int m = 8; m >= 1; m >>= 1) {
            bce  += __shfl_xor(bce, m, 64);
            tmax  = fmaxf(tmax, __shfl_xor(tmax, m, 64));
        }
        if (tc2 == 0)
            sres[s2] = make_float2(bce * (1.0f / (float)NC),
                                   (sigm(tmax) > 0.2f) ? 1.0f : 0.0f);
    }
    __syncthreads();
    if (tid < 64) {
        float bs = 0.f, ca = 0.f;
        if (tid < SPB) { float2 p = sres[tid]; bs = p.x; ca = p.y; }
        for (int m = 32; m >= 1; m >>= 1) {
            bs += __shfl_xor(bs, m, 64);
            ca  = fmaxf(ca, __shfl_xor(ca, m, 64));
        }
        if (tid == 0) g_part[b * CHB + bx] = make_float2(bs, ca);
    }
}

// ---- K2: single block — LDS histogram of g_idx, then coalesced cnt·v dot ----
__global__ __launch_bounds__(1024) void k_final(
    const int*    __restrict__ g_idx,
    const float*  __restrict__ g_v,
    const float2* __restrict__ g_part,
    const int*    __restrict__ tn_p,
    float* __restrict__ out)
{
    __shared__ int   cnt[NB * NQ];   // 57.6 KB (allowed: up to 160 KB/workgroup)
    __shared__ float rb[16], rv[16], rc[16];
    const int tid = threadIdx.x;

    for (int i = tid; i < NB * NQ; i += 1024) cnt[i] = 0;
    __syncthreads();
    #pragma unroll
    for (int k = 0; k < 15; ++k) {
        int i = tid + k * 1024;
        if (i < NB * NQ) {
            int j = g_idx[i];                  // coalesced read
            int b = i / NQ;
            atomicAdd(&cnt[b * NQ + j], 1);    // LDS atomic, deterministic int sum
        }
    }
    __syncthreads();

    float bs = 0.f, ca = 0.f;
    if (tid < NBLK) { float2 p = g_part[tid]; bs = p.x; ca = p.y; }
    float vs = 0.f;
    #pragma unroll
    for (int k = 0; k < 15; ++k) {
        int i = tid + k * 1024;
        if (i < NB * NQ) vs += (float)cnt[i] * g_v[i];   // coalesced, fixed order
    }
    const int wv = tid >> 6, lane = tid & 63;
    for (int m = 32; m >= 1; m >>= 1) {
        bs += __shfl_xor(bs, m, 64);
        vs += __shfl_xor(vs, m, 64);
        ca  = fmaxf(ca, __shfl_xor(ca, m, 64));
    }
    if (lane == 0) { rb[wv] = bs; rv[wv] = vs; rc[wv] = ca; }
    __syncthreads();
    if (tid == 0) {
        float sb = 0.f, sv = 0.f, sc = 0.f;
        for (int k = 0; k < 16; ++k) { sb += rb[k]; sv += rv[k]; sc = fmaxf(sc, rc[k]); }
        float tn = (float)tn_p[0];
        out[0] = (sc > 0.f) ? (sv + sb) / tn : 0.0f;
    }
}

extern "C" void kernel_launch(void* const* d_in, const int* in_sizes, int n_in,
                              void* d_out, int out_size, void* d_ws, size_t ws_size,
                              hipStream_t stream) {
    const float* s_logits = (const float*)d_in[0];
    const float* s_boxes  = (const float*)d_in[1];
    const float* t_logits = (const float*)d_in[2];
    const float* t_boxes  = (const float*)d_in[3];
    const int*   tn       = (const int*)d_in[4];
    float* out = (float*)d_out;

    char* ws = (char*)d_ws;
    int*    g_idx  = (int*)(ws);              // 14400 i32
    float*  g_v    = (float*)(ws + 57600);    // 14400 f32
    float2* g_part = (float2*)(ws + 115200);  // 912 float2

    k_main<<<dim3(CHB, NB), 256, 0, stream>>>(s_logits, s_boxes, t_logits, t_boxes,
                                              g_idx, g_v, g_part);
    k_final<<<1, 1024, 0, stream>>>(g_idx, g_v, g_part, tn, out);
}